// Round 8
// baseline (212.285 us; speedup 1.0000x reference)
//
#include <hip/hip_runtime.h>

typedef __bf16 bf16x8 __attribute__((ext_vector_type(8)));
typedef float f32x4 __attribute__((ext_vector_type(4)));

#define Bdim 8192
#define Nn 36
#define Cc 128
#define EPSf 1e-4f

// ---- d_ws layout (ushort elements): qk hi/lo split, v/proj single-bf16 ----
#define WS_QK_HI 0
#define WS_QK_LO 32768
#define WS_V_HI  65536
#define WS_P_HI  81920
// total 98304 ushorts = 192 KiB

// ---- LDS arena (byte offsets); 40448 B -> 4 blocks/CU (161792 <= 163840) ----
#define OFF_XH   0        // ush [48][128] swz15  x hi          (A->B)
#define OFF_PH   12288    // ush [48][128] swz15  x+pos hi      (A->B)
#define OFF_PL   24576    // ush [48][128] swz15  x+pos lo      (A->B)
#define OFF_KT   0        // ush [128 c][52]      raw k3 bf16   (C->DE) over XH (stride 52)
#define OFF_VT   13312    // ush [128 d][52]      v bf16        (C->DE)
#define OFF_QO   27648    // ush [36][128] swz15  q3 then O     (C->DE->G); G pad-reads to row 47 stay < 39936
#define OFF_MASK 39936    // f32 [48]
#define OFF_VOX  40128    // int [36]
#define OFF_INN  40272    // f32
#define LDS_BYTES 40448

__device__ inline uint bfh(float f) {
    __bf16 h = (__bf16)f;
    return (uint)(*(const ushort*)&h);
}
__device__ inline uint bfl(float f) {
    float hf = (float)((__bf16)f);
    __bf16 l = (__bf16)(f - hf);
    return (uint)(*(const ushort*)&l);
}
__device__ inline uint pk2h(float a, float b) { return bfh(a) | (bfh(b) << 16); }
__device__ inline uint pk2l(float a, float b) { return bfl(a) | (bfl(b) << 16); }

union U8 { bf16x8 v; uint u[4]; };

// ---------------- pre-kernel: weights -> frag-ordered bf16 in ws ----------------
__global__ __launch_bounds__(256)
void prep_frags(const float* __restrict__ qk_w, const float* __restrict__ v_w,
                const float* __restrict__ proj_w, ushort* __restrict__ ws)
{
    int e = blockIdx.x * 256 + threadIdx.x;          // 0..65535
    const float* W; int N; int idx; int hi_off; int lo_off;
    if (e < 32768)      { W = qk_w;   N = 256; hi_off = WS_QK_HI; lo_off = WS_QK_LO; idx = e; }
    else if (e < 49152) { W = v_w;    N = 128; hi_off = WS_V_HI;  lo_off = -1;       idx = e - 32768; }
    else                { W = proj_w; N = 128; hi_off = WS_P_HI;  lo_off = -1;       idx = e - 49152; }
    int j    = idx & 7;
    int lane = (idx >> 3) & 63;
    int ks   = (idx >> 9) & 3;
    int ct   = idx >> 11;
    int col  = ct * 16 + (lane & 15);
    int k    = ks * 32 + (lane >> 4) * 8 + j;
    float v  = W[k * N + col];
    ws[hi_off + idx] = (ushort)bfh(v);
    if (lo_off >= 0) ws[lo_off + idx] = (ushort)bfl(v);
}

// ---------------- main kernel: one block (4 waves, 256 thr) per batch ----------------
__global__ __launch_bounds__(256, 4)
void fla_mfma(const float* __restrict__ x, const float* __restrict__ pos,
              const float* __restrict__ mask, const float* __restrict__ qk_b,
              const float* __restrict__ v_b, const float* __restrict__ proj_b,
              const int* __restrict__ vox, const ushort* __restrict__ ws,
              float* __restrict__ out)
{
    __shared__ __align__(16) char lds[LDS_BYTES];
    const int t = threadIdx.x;
    const int b = blockIdx.x;
    const int lane = t & 63;
    const int wv = t >> 6;                           // 4 waves
    const int  rsel = lane & 15;
    const int  grp  = lane >> 4;
    const uint kgrp = (uint)grp * 8u;
    const uint sw   = ((uint)rsel) << 4;             // row&15 swizzle on frag reads

    // ---------------- Phase A: zero pad rows + stage x(hi), (x+pos)(hi,lo) ----------
    const float* xg = x + (size_t)b * (Nn * Cc);
    const float* pg = pos + (size_t)b * (Nn * Cc);
    #pragma unroll
    for (int i0 = 0; i0 < 3; ++i0) {                 // rows 36..47 of XH/PH/PL := 0
        int i = t + i0 * 256;
        if (i < 576) {
            int reg = i / 192;
            int j = i - reg * 192;
            int row = 36 + (j >> 4);
            int c16 = j & 15;
            *(uint4*)(lds + reg * 12288 + row * 256 + c16 * 16) = make_uint4(0u, 0u, 0u, 0u);
        }
    }
    #pragma unroll
    for (int it = 0; it < 5; ++it) {
        int idx = t + it * 256;                       // 36 rows x 32 float4 = 1152
        if (idx < Nn * 32) {
            int n = idx >> 5;
            int c4 = (idx & 31) << 2;
            float4 xv = *(const float4*)(xg + n * Cc + c4);
            float4 pv = *(const float4*)(pg + n * Cc + c4);
            float s0 = xv.x + pv.x, s1 = xv.y + pv.y;
            float s2 = xv.z + pv.z, s3 = xv.w + pv.w;
            uint ba = (uint)n * 256u + (((uint)(c4 * 2)) ^ (((uint)n & 15u) << 4));
            *(uint2*)(lds + OFF_XH + ba) = make_uint2(pk2h(xv.x, xv.y), pk2h(xv.z, xv.w));
            *(uint2*)(lds + OFF_PH + ba) = make_uint2(pk2h(s0, s1), pk2h(s2, s3));
            *(uint2*)(lds + OFF_PL + ba) = make_uint2(pk2l(s0, s1), pk2l(s2, s3));
        }
    }
    if (t < 48) ((float*)(lds + OFF_MASK))[t] = (t < Nn) ? mask[(size_t)b * Nn + t] : 0.f;
    if (t >= 64 && t < 64 + Nn) ((int*)(lds + OFF_VOX))[t - 64] = vox[(size_t)b * Nn + (t - 64)];
    if (t == 128) {
        float s = 0.f;
        for (int n = 0; n < Nn; ++n) s += mask[(size_t)b * Nn + n];
        *(float*)(lds + OFF_INN) = 1.f / (s + EPSf);
    }
    __syncthreads();

    // ---------------- Phase B: qk GEMM (split-bf16, 4 tiles) + v GEMM (2 tiles) -----
    f32x4 accQ[3][4];
    f32x4 accV[3][2];
    #pragma unroll
    for (int rt = 0; rt < 3; ++rt) {
        #pragma unroll
        for (int ci = 0; ci < 4; ++ci) accQ[rt][ci] = (f32x4){0.f, 0.f, 0.f, 0.f};
        accV[rt][0] = (f32x4){0.f, 0.f, 0.f, 0.f};
        accV[rt][1] = (f32x4){0.f, 0.f, 0.f, 0.f};
    }
    #pragma unroll
    for (int ks = 0; ks < 4; ++ks) {                  // qk: split 3-product
        uint ka = (((uint)(ks * 32) + kgrp) * 2u) ^ sw;
        bf16x8 ph[3], pl[3];
        #pragma unroll
        for (int rt = 0; rt < 3; ++rt) {
            uint ba = (uint)(rt * 16 + rsel) * 256u + ka;
            ph[rt] = *(const bf16x8*)(lds + OFF_PH + ba);
            pl[rt] = *(const bf16x8*)(lds + OFF_PL + ba);
        }
        #pragma unroll
        for (int ci = 0; ci < 4; ++ci) {
            int f = (((wv * 4 + ci) * 4 + ks) * 64 + lane) * 8;
            bf16x8 bh = *(const bf16x8*)(ws + WS_QK_HI + f);
            bf16x8 bl = *(const bf16x8*)(ws + WS_QK_LO + f);
            #pragma unroll
            for (int rt = 0; rt < 3; ++rt) {
                accQ[rt][ci] = __builtin_amdgcn_mfma_f32_16x16x32_bf16(ph[rt], bh, accQ[rt][ci], 0, 0, 0);
                accQ[rt][ci] = __builtin_amdgcn_mfma_f32_16x16x32_bf16(ph[rt], bl, accQ[rt][ci], 0, 0, 0);
                accQ[rt][ci] = __builtin_amdgcn_mfma_f32_16x16x32_bf16(pl[rt], bh, accQ[rt][ci], 0, 0, 0);
            }
        }
    }
    #pragma unroll
    for (int ks = 0; ks < 4; ++ks) {                  // v: A = x(hi) only
        uint ka = (((uint)(ks * 32) + kgrp) * 2u) ^ sw;
        bf16x8 xh[3];
        #pragma unroll
        for (int rt = 0; rt < 3; ++rt)
            xh[rt] = *(const bf16x8*)(lds + OFF_XH + (uint)(rt * 16 + rsel) * 256u + ka);
        #pragma unroll
        for (int ci = 0; ci < 2; ++ci) {
            int f = (((wv * 2 + ci) * 4 + ks) * 64 + lane) * 8;
            bf16x8 bvh = *(const bf16x8*)(ws + WS_V_HI + f);
            #pragma unroll
            for (int rt = 0; rt < 3; ++rt)
                accV[rt][ci] = __builtin_amdgcn_mfma_f32_16x16x32_bf16(xh[rt], bvh, accV[rt][ci], 0, 0, 0);
        }
    }
    __syncthreads();   // staging dead; C may overwrite

    // ---------------- Phase C: epilogues -> VT, QH(raw q3), KT(raw k3) --------------
    const float* sM = (const float*)(lds + OFF_MASK);
    {   // v: +bias -> bf16 -> VT[d=col][n] (stride 52)
        #pragma unroll
        for (int ci = 0; ci < 2; ++ci) {
            int colv = (wv * 2 + ci) * 16 + rsel;
            float vb = v_b[colv];
            #pragma unroll
            for (int rt = 0; rt < 3; ++rt) {
                float a0 = accV[rt][ci][0] + vb, a1 = accV[rt][ci][1] + vb;
                float a2 = accV[rt][ci][2] + vb, a3 = accV[rt][ci][3] + vb;
                uint addr = OFF_VT + (uint)(colv * 52 + rt * 16 + grp * 4) * 2u;
                *(uint2*)(lds + addr) = make_uint2(pk2h(a0, a1), pk2h(a2, a3));
            }
        }
    }
    if (wv < 2) {       // q: +bias, cube -> QO scatter (rows<36)
        #pragma unroll
        for (int ci = 0; ci < 4; ++ci) {
            int colq = (wv * 4 + ci) * 16 + rsel;
            float qb = qk_b[colq];
            uint cb2 = (uint)(colq * 2);
            #pragma unroll
            for (int rt = 0; rt < 3; ++rt) {
                #pragma unroll
                for (int r = 0; r < 4; ++r) {
                    int row = rt * 16 + grp * 4 + r;
                    if (row < Nn) {
                        float q1 = accQ[rt][ci][r] + qb;
                        float q3 = q1 * q1 * q1;
                        uint ba = (uint)row * 256u + (cb2 ^ (((uint)row & 15u) << 4));
                        *(ushort*)(lds + OFF_QO + ba) = (ushort)bfh(q3);
                    }
                }
            }
        }
    } else {            // k: +bias, *mask, cube -> KT[c=col][n] (stride 52)
        #pragma unroll
        for (int ci = 0; ci < 4; ++ci) {
            int colk = ((wv - 2) * 4 + ci) * 16 + rsel;
            float kb = qk_b[Cc + colk];
            #pragma unroll
            for (int rt = 0; rt < 3; ++rt) {
                float k3v[4];
                #pragma unroll
                for (int r = 0; r < 4; ++r) {
                    int row = rt * 16 + grp * 4 + r;
                    float k1 = (accQ[rt][ci][r] + kb) * sM[row];
                    k3v[r] = k1 * k1 * k1;
                }
                uint addr = OFF_KT + (uint)(colk * 52 + rt * 16 + grp * 4) * 2u;
                *(uint2*)(lds + addr) = make_uint2(pk2h(k3v[0], k3v[1]), pk2h(k3v[2], k3v[3]));
            }
        }
    }
    __syncthreads();

    // ---------------- Phase DE: heads {2wv, 2wv+1}; kv kept in registers -------------
    {
        uint bkvU[2][4];
        #pragma unroll
        for (int hh = 0; hh < 2; ++hh) {
            int h = wv * 2 + hh;
            int col16 = h * 16 + rsel;               // c (A-row) and d (B-col) index
            uint a0 = OFF_KT + (uint)(col16 * 52 + grp * 8) * 2u;
            uint b0 = OFF_VT + (uint)(col16 * 52 + grp * 8) * 2u;
            bf16x8 kA0 = *(const bf16x8*)(lds + a0);
            bf16x8 vB0 = *(const bf16x8*)(lds + b0);
            U8 kA1, vB1;
            kA1.u[0] = kA1.u[1] = kA1.u[2] = kA1.u[3] = 0u;
            vB1.u[0] = vB1.u[1] = vB1.u[2] = vB1.u[3] = 0u;
            if (grp < 2) {                           // n = 32 + grp*8 .. +7
                kA1.v = *(const bf16x8*)(lds + a0 + 64);
                vB1.v = *(const bf16x8*)(lds + b0 + 64);
            }
            // column norm of raw k3 (same bf16 values the MFMA consumes)
            float s = 0.f;
            #pragma unroll
            for (int j = 0; j < 8; ++j) { float q = (float)kA0[j]; s += q * q; }
            #pragma unroll
            for (int j = 0; j < 8; ++j) { float q = (float)kA1.v[j]; s += q * q; }
            s += __shfl_xor(s, 16);
            s += __shfl_xor(s, 32);
            float invkn = 1.f / (EPSf + sqrtf(s));

            f32x4 kvacc = (f32x4){0.f, 0.f, 0.f, 0.f};
            kvacc = __builtin_amdgcn_mfma_f32_16x16x32_bf16(kA0, vB0, kvacc, 0, 0, 0);
            kvacc = __builtin_amdgcn_mfma_f32_16x16x32_bf16(kA1.v, vB1.v, kvacc, 0, 0, 0);
            #pragma unroll
            for (int r = 0; r < 4; ++r)
                kvacc[r] *= __shfl(invkn, grp * 4 + r);   // scale by invkn[c=grp*4+r]

            // redistribute kv[c][d] -> E's B-frag: bkv[j] = kv[c=grp*8+j][d=rsel]
            float bv[8];
            #pragma unroll
            for (int j = 0; j < 8; ++j)
                bv[j] = __shfl(kvacc[j & 3], rsel + 16 * (2 * grp + (j >> 2)));
            if (grp >= 2) {
                #pragma unroll
                for (int j = 0; j < 8; ++j) bv[j] = 0.f;  // k=c >= 16 lanes must be zero
            }
            bkvU[hh][0] = pk2h(bv[0], bv[1]);
            bkvU[hh][1] = pk2h(bv[2], bv[3]);
            bkvU[hh][2] = pk2h(bv[4], bv[5]);
            bkvU[hh][3] = pk2h(bv[6], bv[7]);
        }

        // E: read all q3 fragments first (wave-private col range), then write O
        float inn = *(const float*)(lds + OFF_INN);
        U8 aq[2][3];
        #pragma unroll
        for (int hh = 0; hh < 2; ++hh) {
            uint cb = (uint)((wv * 2 + hh) * 32 + grp * 16);
            #pragma unroll
            for (int rt = 0; rt < 3; ++rt) {
                int row = rt * 16 + rsel;
                aq[hh][rt].u[0] = aq[hh][rt].u[1] = aq[hh][rt].u[2] = aq[hh][rt].u[3] = 0u;
                if (grp < 2 && row < Nn)
                    aq[hh][rt].v = *(const bf16x8*)(lds + OFF_QO + (uint)row * 256u + (cb ^ sw));
            }
        }
        f32x4 oacc[2][3];
        float invn[2][3];
        #pragma unroll
        for (int hh = 0; hh < 2; ++hh) {
            U8 bkv;
            bkv.u[0] = bkvU[hh][0]; bkv.u[1] = bkvU[hh][1];
            bkv.u[2] = bkvU[hh][2]; bkv.u[3] = bkvU[hh][3];
            #pragma unroll
            for (int rt = 0; rt < 3; ++rt) {
                float s = 0.f;
                #pragma unroll
                for (int j = 0; j < 8; ++j) { float q = (float)aq[hh][rt].v[j]; s += q * q; }
                s += __shfl_xor(s, 16);               // head-local row norm (lanes 0..31 valid)
                invn[hh][rt] = 1.f / (EPSf + sqrtf(s));
                f32x4 o = (f32x4){0.f, 0.f, 0.f, 0.f};
                o = __builtin_amdgcn_mfma_f32_16x16x32_bf16(aq[hh][rt].v, bkv.v, o, 0, 0, 0);
                oacc[hh][rt] = o;
            }
        }
        #pragma unroll
        for (int hh = 0; hh < 2; ++hh) {
            int h = wv * 2 + hh;
            uint cb2 = (uint)((h * 16 + rsel) * 2);
            #pragma unroll
            for (int rt = 0; rt < 3; ++rt) {
                #pragma unroll
                for (int r = 0; r < 4; ++r) {
                    int rr = grp * 4 + r;
                    int row = rt * 16 + rr;
                    if (row < Nn) {
                        float fac = __shfl(invn[hh][rt], rr) * inn;
                        float val = oacc[hh][rt][r] * fac;
                        uint ba = (uint)row * 256u + (cb2 ^ (((uint)row & 15u) << 4));
                        *(ushort*)(lds + OFF_QO + ba) = (ushort)bfh(val);
                    }
                }
            }
        }
    }
    __syncthreads();

    // ---------------- Phase G: proj GEMM (single-bf16, 2 tiles) + scatter ------------
    f32x4 accP[3][2];
    #pragma unroll
    for (int rt = 0; rt < 3; ++rt) {
        accP[rt][0] = (f32x4){0.f, 0.f, 0.f, 0.f};
        accP[rt][1] = (f32x4){0.f, 0.f, 0.f, 0.f};
    }
    #pragma unroll
    for (int ks = 0; ks < 4; ++ks) {
        uint ka = (((uint)(ks * 32) + kgrp) * 2u) ^ sw;
        bf16x8 oa[3];
        #pragma unroll
        for (int rt = 0; rt < 3; ++rt)
            oa[rt] = *(const bf16x8*)(lds + OFF_QO + (uint)(rt * 16 + rsel) * 256u + ka);
        #pragma unroll
        for (int ci = 0; ci < 2; ++ci) {
            int f = (((wv * 2 + ci) * 4 + ks) * 64 + lane) * 8;
            bf16x8 bp = *(const bf16x8*)(ws + WS_P_HI + f);
            #pragma unroll
            for (int rt = 0; rt < 3; ++rt)
                accP[rt][ci] = __builtin_amdgcn_mfma_f32_16x16x32_bf16(oa[rt], bp, accP[rt][ci], 0, 0, 0);
        }
    }
    {
        const int* sVx = (const int*)(lds + OFF_VOX);
        #pragma unroll
        for (int ci = 0; ci < 2; ++ci) {
            int col = (wv * 2 + ci) * 16 + rsel;
            float pb = proj_b[col];
            #pragma unroll
            for (int rt = 0; rt < 3; ++rt) {
                #pragma unroll
                for (int r = 0; r < 4; ++r) {
                    int row = rt * 16 + grp * 4 + r;
                    if (row < Nn)
                        out[(size_t)sVx[row] * Cc + col] = accP[rt][ci][r] + pb;
                }
            }
        }
    }
}

extern "C" void kernel_launch(void* const* d_in, const int* in_sizes, int n_in,
                              void* d_out, int out_size, void* d_ws, size_t ws_size,
                              hipStream_t stream) {
    (void)in_sizes; (void)n_in; (void)out_size; (void)ws_size;
    const float* x      = (const float*)d_in[0];
    const float* pos    = (const float*)d_in[1];
    const float* mask   = (const float*)d_in[2];
    const float* qk_w   = (const float*)d_in[3];
    const float* qk_b   = (const float*)d_in[4];
    const float* v_w    = (const float*)d_in[5];
    const float* v_b    = (const float*)d_in[6];
    const float* proj_w = (const float*)d_in[7];
    const float* proj_b = (const float*)d_in[8];
    // d_in[9] = coords (unused)
    const int*   vox    = (const int*)d_in[10];
    ushort* ws = (ushort*)d_ws;            // 192 KiB scratch used
    float* outp = (float*)d_out;

    hipLaunchKernelGGL(prep_frags, dim3(256), dim3(256), 0, stream, qk_w, v_w, proj_w, ws);
    hipLaunchKernelGGL(fla_mfma, dim3(Bdim), dim3(256), 0, stream,
                       x, pos, mask, qk_b, v_b, proj_b, vox, ws, outp);
}